// Round 13
// baseline (928.572 us; speedup 1.0000x reference)
//
#include <hip/hip_runtime.h>
#include <hip/hip_bf16.h>

#define RESN 64
#define NS 24
#define WD 256
#define SD 256
#define NB 2
#define RPB 4          // rays per block
#define MP 96          // points per block = RPB*NS
#define NTH 512
#define NBLK 2048      // (NB*RESN*RESN)/RPB

typedef unsigned short u16;
typedef unsigned int u32;
typedef __attribute__((ext_vector_type(8))) short short8v;   // 8 bf16 (4 VGPRs)
typedef __attribute__((ext_vector_type(16))) float f32x16;   // MFMA 32x32 accumulator

__device__ __forceinline__ float sigm(float x){ return 1.0f / (1.0f + expf(-x)); }

// range-reduced odd deg-9 sin, |x| <= ~100, abs err ~4e-6
__device__ __forceinline__ float fast_sin(float x){
  float k = __builtin_rintf(x * 0.31830988618f);
  float y = fmaf(k, -3.14159274101f, x);
  y = fmaf(k, 8.74227766e-8f, y);
  float y2 = y * y;
  float p = fmaf(y2, 2.75573192e-6f, -1.98412698e-4f);
  p = fmaf(y2, p, 8.33333333e-3f);
  p = fmaf(y2, p, -1.66666667e-1f);
  float s = fmaf(y * y2, p, y);
  u32 sg = ((u32)((int)k) & 1u) << 31;
  return __uint_as_float(__float_as_uint(s) ^ sg);
}

// ---------------- kernel 0: split fp32 weights into bf16 hi/lo planes ----------------
__global__ void prep_kernel(const float* wsp, const float* vw, u16* Whi, u16* Wlo){
  int i0 = (blockIdx.x * 256 + threadIdx.x) * 4;
  #pragma unroll
  for (int j = 0; j < 4; j++){
    int e = i0 + j;
    int lay = e >> 16;
    int rk = e & 65535;
    float w = (lay < 7) ? wsp[lay * 65536 + rk]
                        : vw[(size_t)(rk >> 8) * 259 + (rk & 255)];
    u32 b = __float_as_uint(w);
    u16 hi = (u16)(b >> 16);
    float lof = w - __uint_as_float(b & 0xFFFF0000u);
    Whi[e] = hi;
    Wlo[e] = (u16)(__float_as_uint(lof) >> 16);
  }
}

// ---------------- kernel 1: FiLM gamma/beta per (layer, batch, out) ----------------
__global__ void film_kernel(const float* styles, const float* gw8, const float* gb8,
                            const float* bw8, const float* bb8,
                            const float* vgw, const float* vgb, const float* vbw, const float* vbb,
                            float* G, float* Bt){
  int l = blockIdx.x >> 1, b = blockIdx.x & 1, o = threadIdx.x;
  __shared__ float st[SD];
  st[o] = styles[b * SD + o];
  __syncthreads();
  const float *gw, *bw; float gbv, bbv;
  if (l < 8){
    gw = gw8 + ((size_t)l * WD + o) * SD; bw = bw8 + ((size_t)l * WD + o) * SD;
    gbv = gb8[l * WD + o];                bbv = bb8[l * WD + o];
  } else {
    gw = vgw + (size_t)o * SD;            bw = vbw + (size_t)o * SD;
    gbv = vgb[o];                         bbv = vbb[o];
  }
  float ag = 0.f, ab = 0.f;
  for (int s = 0; s < SD; s += 2){
    ag += st[s] * gw[s] + st[s+1] * gw[s+1];
    ab += st[s] * bw[s] + st[s+1] * bw[s+1];
  }
  int idx = (l * NB + b) * WD + o;
  G[idx]  = 15.0f * (ag + gbv) + 30.0f;
  Bt[idx] = 0.25f * (ab + bbv);
}

// ---------------- kernel 2: fused MFMA renderer ----------------
// 512 threads = 8 waves. Wave w owns output cols [w*32, w*32+32).
// H planes: slot(row, chunk) = chunk ^ (row & 31)  -- FULL-ROW swizzle.
// KMAIN read slot = ce ^ lane31: full 0..31 permutation across lanes ->
// minimum-cycle ds_read_b128 (old row&7 form was a 4-way bank conflict).
#define SETW(LAY) { wph = Whi + (((size_t)(LAY) * WD + col) * WD) + khalf * 8;   \
                    wpl = Wlo + (((size_t)(LAY) * WD + col) * WD) + khalf * 8; }

#define PREF4 { _Pragma("unroll")                                                \
  for (int i = 0; i < 4; i++){                                                   \
    pbh[i] = *(const short8v*)(wph + i * 16);                                    \
    pbl[i] = *(const short8v*)(wpl + i * 16); } }

#define KMAIN                                                                    \
  _Pragma("unroll")                                                              \
  for (int ks = 0; ks < 16; ks++){                                               \
    short8v bh = pbh[ks & 3], bl = pbl[ks & 3];                                  \
    if (ks < 12){ pbh[ks & 3] = *(const short8v*)(wph + (ks + 4) * 16);          \
                  pbl[ks & 3] = *(const short8v*)(wpl + (ks + 4) * 16); }        \
    int ce = 2 * ks + khalf;                                                     \
    _Pragma("unroll")                                                            \
    for (int mt = 0; mt < 3; mt++){                                              \
      int elem = (mt * 32 + lane31) * WD + ((ce ^ lane31) * 8);                  \
      short8v ah = *(const short8v*)(&Hhi[elem]);                                \
      short8v al = *(const short8v*)(&Hlo[elem]);                                \
      acc[mt] = __builtin_amdgcn_mfma_f32_32x32x16_bf16(ah, bh, acc[mt], 0,0,0); \
      acc[mt] = __builtin_amdgcn_mfma_f32_32x32x16_bf16(al, bh, acc[mt], 0,0,0); \
      acc[mt] = __builtin_amdgcn_mfma_f32_32x32x16_bf16(ah, bl, acc[mt], 0,0,0); \
    } }

__launch_bounds__(NTH, 2)
__global__ void render_mfma(
    const float* pose, const float* focal, const float* nearv, const float* farv,
    const float* w0, const float* b0, const float* bsp,
    const float* vw, const float* vb,
    const float* rgbw, const float* rgbb, const float* sgw, const float* sgb,
    const float* sbeta, const float* G, const float* Bt,
    const u16* Whi, const u16* Wlo, float* out)
{
  __shared__ u16 Hhi[MP * WD];          // 48 KB
  __shared__ u16 Hlo[MP * WD];          // 48 KB
  __shared__ float xl[MP][4];
  __shared__ float vd[RPB][4];
  __shared__ float dn[RPB];
  __shared__ float sdfl[MP];
  __shared__ float rgbl[MP][4];
  __shared__ float wtl[RPB][NS];
  __shared__ float swl[WD];
  __shared__ float rwl[3][WD];

  const int t      = threadIdx.x;
  const int lane   = t & 63;
  const int wv     = t >> 6;
  const int lane31 = lane & 31;
  const int khalf  = lane >> 5;
  const int col    = wv * 32 + lane31;
  const int om     = t & 127;
  const int mg     = t >> 7;
  const int o0     = om * 2, o1 = om * 2 + 1;
  const int mb     = mg * NS;
  const int ray0   = blockIdx.x * RPB;
  const int bidx   = ray0 >> 12;

  // B prefetch state (persists across layers)
  const u16 *wph, *wpl;
  short8v pbh[4], pbl[4];
  SETW(0); PREF4;                      // layer-0 weights fly during setup

  if (t < WD) swl[t] = sgw[t];
  for (int i = t; i < 3 * WD; i += NTH) ((float*)rwl)[i] = rgbw[i];

  // ---- point setup ----
  if (t < MP){
    int m = t, s = m % NS, rl = m / NS;
    int ray = ray0 + rl;
    int ww = ray & (RESN - 1);
    int hh = (ray >> 6) & (RESN - 1);
    float f = focal[bidx], nr = nearv[bidx], fr = farv[bidx];
    float di = ((ww + 0.5f) - RESN * 0.5f) / f;
    float dj = -(((hh + 0.5f) - RESN * 0.5f) / f);
    const float* P = pose + bidx * 12;
    float rdx = di * P[0] + dj * P[1] - P[2];
    float rdy = di * P[4] + dj * P[5] - P[6];
    float rdz = di * P[8] + dj * P[9] - P[10];
    float ox = P[3], oy = P[7], oz = P[11];
    float nrm = sqrtf(rdx * rdx + rdy * rdy + rdz * rdz);
    const float C = (1.0f - 1.0f / NS) / (NS - 1);
    float tv = s * C;
    float z = nr * (1.0f - tv) + fr * tv;
    float sc = 2.0f / (fr - nr);
    xl[m][0] = (ox + rdx * z) * sc;
    xl[m][1] = (oy + rdy * z) * sc;
    xl[m][2] = (oz + rdz * z) * sc;
    if (s == 0){
      vd[rl][0] = rdx / nrm; vd[rl][1] = rdy / nrm; vd[rl][2] = rdz / nrm;
      dn[rl] = nrm;
    }
  }
  __syncthreads();

  // ---- layer 0: 3 -> 256 (VALU), writes bf16 hi/lo planes ----
  {
    float wa[3], wbv[3];
    #pragma unroll
    for (int j = 0; j < 3; j++){ wa[j] = w0[o0 * 3 + j]; wbv[j] = w0[o1 * 3 + j]; }
    float bi0 = b0[o0], bi1 = b0[o1];
    float g0 = G[bidx * WD + o0],  g1 = G[bidx * WD + o1];
    float e0 = Bt[bidx * WD + o0], e1 = Bt[bidx * WD + o1];
    #pragma unroll
    for (int m = 0; m < NS; m++){
      int row = mb + m;
      float x0 = xl[row][0], x1 = xl[row][1], x2 = xl[row][2];
      float u0 = x0 * wa[0]  + x1 * wa[1]  + x2 * wa[2]  + bi0;
      float u1 = x0 * wbv[0] + x1 * wbv[1] + x2 * wbv[2] + bi1;
      float s0 = fast_sin(fmaf(g0, u0, e0));
      float s1 = fast_sin(fmaf(g1, u1, e1));
      u32 bs0 = __float_as_uint(s0), bs1 = __float_as_uint(s1);
      u32 hw = (bs0 >> 16) | (bs1 & 0xFFFF0000u);
      float l0f = s0 - __uint_as_float(bs0 & 0xFFFF0000u);
      float l1f = s1 - __uint_as_float(bs1 & 0xFFFF0000u);
      u32 lw = (__float_as_uint(l0f) >> 16) | (__float_as_uint(l1f) & 0xFFFF0000u);
      int eidx = row * WD + (((o0 >> 3) ^ (row & 31)) * 8) + (o0 & 7);
      *(u32*)&Hhi[eidx] = hw;
      *(u32*)&Hlo[eidx] = lw;
    }
  }
  __syncthreads();

  // ---- 7 hidden layers via MFMA ----
  #pragma unroll 1
  for (int l = 0; l < 7; l++){
    f32x16 acc[3];
    #pragma unroll
    for (int mt = 0; mt < 3; mt++)
      #pragma unroll
      for (int j = 0; j < 16; j++) acc[mt][j] = 0.f;
    KMAIN
    float g  = G[((l + 1) * NB + bidx) * WD + col];
    float e  = Bt[((l + 1) * NB + bidx) * WD + col];
    float bi = bsp[l * WD + col];
    __syncthreads();   // everyone done reading planes
    #pragma unroll
    for (int mt = 0; mt < 3; mt++){
      #pragma unroll
      for (int rg = 0; rg < 16; rg++){
        int row = mt * 32 + (rg & 3) + 8 * (rg >> 2) + 4 * khalf;
        float a = acc[mt][rg] + bi;
        float s = fast_sin(fmaf(g, a, e));
        u32 sb = __float_as_uint(s);
        int eidx = row * WD + ((((col >> 3) ^ (row & 31))) * 8) + (col & 7);
        Hhi[eidx] = (u16)(sb >> 16);
        float sl = s - __uint_as_float(sb & 0xFFFF0000u);
        Hlo[eidx] = (u16)(__float_as_uint(sl) >> 16);
      }
    }
    SETW(l + 1); PREF4;   // next layer's (or view layer's) first 4 B-chunks
    __syncthreads();
  }

  // ---- view layer K-loop (lay 7 of planes, prefetched in last iteration) ----
  f32x16 acc[3];
  #pragma unroll
  for (int mt = 0; mt < 3; mt++)
    #pragma unroll
    for (int j = 0; j < 16; j++) acc[mt][j] = 0.f;
  KMAIN
  // view tail weights (cols 256..258) + bias, per output col
  float vt0 = vw[(size_t)col * 259 + 256];
  float vt1 = vw[(size_t)col * 259 + 257];
  float vt2 = vw[(size_t)col * 259 + 258];
  float vbv = vb[col];
  float gv = G[(8 * NB + bidx) * WD + col];
  float ev = Bt[(8 * NB + bidx) * WD + col];

  // ---- sigma head (reads layer-7 planes, before epilogue overwrites) ----
  if (t < MP){
    float a = 0.f;
    #pragma unroll 4
    for (int c = 0; c < 32; c++){
      int eb = t * WD + ((c ^ (t & 31)) * 8);
      short8v hv = *(const short8v*)(&Hhi[eb]);
      short8v lv = *(const short8v*)(&Hlo[eb]);
      #pragma unroll
      for (int j = 0; j < 8; j++){
        float h = __uint_as_float(((u32)(u16)hv[j]) << 16)
                + __uint_as_float(((u32)(u16)lv[j]) << 16);
        a = fmaf(h, swl[c * 8 + j], a);
      }
    }
    sdfl[t] = a + sgb[0];
  }
  __syncthreads();

  // ---- view epilogue: feat = sin(g*(acc + dir-term) + e) -> planes ----
  #pragma unroll
  for (int mt = 0; mt < 3; mt++){
    #pragma unroll
    for (int rg = 0; rg < 16; rg++){
      int row = mt * 32 + (rg & 3) + 8 * (rg >> 2) + 4 * khalf;
      int ray = (row >= 48) ? ((row >= 72) ? 3 : 2) : ((row >= 24) ? 1 : 0);
      float c = vd[ray][0] * vt0 + vd[ray][1] * vt1 + vd[ray][2] * vt2 + vbv;
      float a = acc[mt][rg] + c;
      float s = fast_sin(fmaf(gv, a, ev));
      u32 sb = __float_as_uint(s);
      int eidx = row * WD + ((((col >> 3) ^ (row & 31))) * 8) + (col & 7);
      Hhi[eidx] = (u16)(sb >> 16);
      float sl = s - __uint_as_float(sb & 0xFFFF0000u);
      Hlo[eidx] = (u16)(__float_as_uint(sl) >> 16);
    }
  }
  __syncthreads();

  // ---- rgb head (reads feat planes) ----
  if (t < MP){
    float a0 = 0.f, a1 = 0.f, a2 = 0.f;
    #pragma unroll 4
    for (int c = 0; c < 32; c++){
      int eb = t * WD + ((c ^ (t & 31)) * 8);
      short8v hv = *(const short8v*)(&Hhi[eb]);
      short8v lv = *(const short8v*)(&Hlo[eb]);
      #pragma unroll
      for (int j = 0; j < 8; j++){
        float h = __uint_as_float(((u32)(u16)hv[j]) << 16)
                + __uint_as_float(((u32)(u16)lv[j]) << 16);
        int k = c * 8 + j;
        a0 = fmaf(h, rwl[0][k], a0);
        a1 = fmaf(h, rwl[1][k], a1);
        a2 = fmaf(h, rwl[2][k], a2);
      }
    }
    rgbl[t][0] = a0 + rgbb[0];
    rgbl[t][1] = a1 + rgbb[1];
    rgbl[t][2] = a2 + rgbb[2];
  }
  __syncthreads();

  // ---- volume integration weights + rgb_map (one thread per ray) ----
  if (t < RPB){
    int r = t;
    int ray = ray0 + r;
    float nr = nearv[bidx], fr = farv[bidx];
    float dnv = dn[r];
    float bet = sbeta[0];
    float vis = 1.f, wsum = 0.f, cr = 0.f, cg = 0.f, cb = 0.f;
    const float C = (1.0f - 1.0f / NS) / (NS - 1);
    #pragma unroll
    for (int s = 0; s < NS; s++){
      float w;
      if (s < NS - 1){
        float t0v = s * C, t1v = (s + 1) * C;
        float z0 = nr * (1.f - t0v) + fr * t0v;
        float z1 = nr * (1.f - t1v) + fr * t1v;
        float dist = (z1 - z0) * dnv;
        float sg = sigm(-sdfl[r * NS + s] / bet) / bet;
        float al = 1.f - expf(-sg * dist);
        w = al * vis;
        vis *= (1.f - al + 1e-10f);
        wsum += w;
      } else {
        w = 1.f - wsum;
      }
      wtl[r][s] = w;
      cr += w * sigm(rgbl[r * NS + s][0]);
      cg += w * sigm(rgbl[r * NS + s][1]);
      cb += w * sigm(rgbl[r * NS + s][2]);
    }
    size_t ob = (size_t)ray * 259;
    out[ob + 0] = -1.f + 2.f * cr;
    out[ob + 1] = -1.f + 2.f * cg;
    out[ob + 2] = -1.f + 2.f * cb;
  }
  __syncthreads();

  // ---- feature map: sum_s w_s * feat_s ----
  {
    float f0 = 0.f, f1 = 0.f;
    #pragma unroll
    for (int s = 0; s < NS; s++){
      int row = mb + s;
      float w = wtl[mg][s];
      int eidx = row * WD + (((o0 >> 3) ^ (row & 31)) * 8) + (o0 & 7);
      u32 wh = *(const u32*)&Hhi[eidx];
      u32 wl = *(const u32*)&Hlo[eidx];
      float fa = __uint_as_float(wh << 16) + __uint_as_float(wl << 16);
      float fb = __uint_as_float(wh & 0xFFFF0000u) + __uint_as_float(wl & 0xFFFF0000u);
      f0 = fmaf(w, fa, f0);
      f1 = fmaf(w, fb, f1);
    }
    size_t ob = (size_t)(ray0 + mg) * 259 + 3;
    out[ob + o0] = f0;
    out[ob + o1] = f1;
  }
}

extern "C" void kernel_launch(void* const* d_in, const int* in_sizes, int n_in,
                              void* d_out, int out_size, void* d_ws, size_t ws_size,
                              hipStream_t stream) {
  (void)in_sizes; (void)n_in; (void)out_size; (void)ws_size;
  const float* pose   = (const float*)d_in[0];
  const float* focal  = (const float*)d_in[1];
  const float* nearv  = (const float*)d_in[2];
  const float* farv   = (const float*)d_in[3];
  const float* styles = (const float*)d_in[4];
  const float* w0     = (const float*)d_in[5];
  const float* b0     = (const float*)d_in[6];
  const float* wsp    = (const float*)d_in[7];
  const float* bsp    = (const float*)d_in[8];
  const float* gw8    = (const float*)d_in[9];
  const float* gb8    = (const float*)d_in[10];
  const float* bw8    = (const float*)d_in[11];
  const float* bb8    = (const float*)d_in[12];
  const float* vw     = (const float*)d_in[13];
  const float* vb     = (const float*)d_in[14];
  const float* vgw    = (const float*)d_in[15];
  const float* vgb    = (const float*)d_in[16];
  const float* vbw    = (const float*)d_in[17];
  const float* vbb    = (const float*)d_in[18];
  const float* rgbw   = (const float*)d_in[19];
  const float* rgbb   = (const float*)d_in[20];
  const float* sgw    = (const float*)d_in[21];
  const float* sgb    = (const float*)d_in[22];
  const float* sbeta  = (const float*)d_in[23];

  float* G  = (float*)d_ws;
  float* Bt = G + 9 * NB * WD;                       // 4608 floats
  float* out = (float*)d_out;

  const size_t plane_off = 36864;                    // bytes (G+Bt)
  const size_t plane_elems = (size_t)8 * WD * WD;    // 524288 u16 per plane

  u16* Whi = (u16*)((char*)d_ws + plane_off);
  u16* Wlo = Whi + plane_elems;

  film_kernel<<<dim3(18), dim3(256), 0, stream>>>(styles, gw8, gb8, bw8, bb8,
                                                  vgw, vgb, vbw, vbb, G, Bt);
  prep_kernel<<<dim3(512), dim3(256), 0, stream>>>(wsp, vw, Whi, Wlo);
  render_mfma<<<dim3(NBLK), dim3(NTH), 0, stream>>>(pose, focal, nearv, farv,
      w0, b0, bsp, vw, vb, rgbw, rgbb, sgw, sgb, sbeta, G, Bt, Whi, Wlo, out);
}

// Round 14
// 903.278 us; speedup vs baseline: 1.0280x; 1.0280x over previous
//
#include <hip/hip_runtime.h>
#include <hip/hip_bf16.h>

#define RESN 64
#define NS 24
#define WD 256
#define SD 256
#define NB 2
#define RPB 4          // rays per block
#define MP 96          // points per block = RPB*NS
#define NTH 512
#define NBLK 2048      // (NB*RESN*RESN)/RPB

typedef unsigned short u16;
typedef unsigned int u32;
typedef __attribute__((ext_vector_type(8))) short short8v;   // 8 bf16 (4 VGPRs)
typedef __attribute__((ext_vector_type(16))) float f32x16;   // MFMA 32x32 accumulator

__device__ __forceinline__ float sigm(float x){ return 1.0f / (1.0f + expf(-x)); }

// range-reduced odd deg-9 sin, |x| <= ~100, abs err ~4e-6
__device__ __forceinline__ float fast_sin(float x){
  float k = __builtin_rintf(x * 0.31830988618f);
  float y = fmaf(k, -3.14159274101f, x);
  y = fmaf(k, 8.74227766e-8f, y);
  float y2 = y * y;
  float p = fmaf(y2, 2.75573192e-6f, -1.98412698e-4f);
  p = fmaf(y2, p, 8.33333333e-3f);
  p = fmaf(y2, p, -1.66666667e-1f);
  float s = fmaf(y * y2, p, y);
  u32 sg = ((u32)((int)k) & 1u) << 31;
  return __uint_as_float(__float_as_uint(s) ^ sg);
}

// ---------------- kernel 0: split fp32 weights into bf16 hi/lo planes ----------------
__global__ void prep_kernel(const float* wsp, const float* vw, u16* Whi, u16* Wlo){
  int i0 = (blockIdx.x * 256 + threadIdx.x) * 4;
  #pragma unroll
  for (int j = 0; j < 4; j++){
    int e = i0 + j;
    int lay = e >> 16;
    int rk = e & 65535;
    float w = (lay < 7) ? wsp[lay * 65536 + rk]
                        : vw[(size_t)(rk >> 8) * 259 + (rk & 255)];
    u32 b = __float_as_uint(w);
    u16 hi = (u16)(b >> 16);
    float lof = w - __uint_as_float(b & 0xFFFF0000u);
    Whi[e] = hi;
    Wlo[e] = (u16)(__float_as_uint(lof) >> 16);
  }
}

// ---------------- kernel 1: FiLM gamma/beta per (layer, batch, out) ----------------
__global__ void film_kernel(const float* styles, const float* gw8, const float* gb8,
                            const float* bw8, const float* bb8,
                            const float* vgw, const float* vgb, const float* vbw, const float* vbb,
                            float* G, float* Bt){
  int l = blockIdx.x >> 1, b = blockIdx.x & 1, o = threadIdx.x;
  __shared__ float st[SD];
  st[o] = styles[b * SD + o];
  __syncthreads();
  const float *gw, *bw; float gbv, bbv;
  if (l < 8){
    gw = gw8 + ((size_t)l * WD + o) * SD; bw = bw8 + ((size_t)l * WD + o) * SD;
    gbv = gb8[l * WD + o];                bbv = bb8[l * WD + o];
  } else {
    gw = vgw + (size_t)o * SD;            bw = vbw + (size_t)o * SD;
    gbv = vgb[o];                         bbv = vbb[o];
  }
  float ag = 0.f, ab = 0.f;
  for (int s = 0; s < SD; s += 2){
    ag += st[s] * gw[s] + st[s+1] * gw[s+1];
    ab += st[s] * bw[s] + st[s+1] * bw[s+1];
  }
  int idx = (l * NB + b) * WD + o;
  G[idx]  = 15.0f * (ag + gbv) + 30.0f;
  Bt[idx] = 0.25f * (ab + bbv);
}

// ---------------- kernel 2: fused MFMA renderer ----------------
// 512 threads = 8 waves. Wave w owns output cols [w*32, w*32+32).
// H planes: slot(row, chunk) = chunk ^ (row & 31) -- full-row swizzle,
// conflict-free KMAIN reads (proven r13: 5.2e7 -> 1.5e5 conflicts).
// No B-prefetch ring (frees ~34 arch VGPRs -> avoid r13's spill);
// B loads issue directly inside the fully-unrolled K-loop.
#define KMAIN(LAY)                                                               \
{ const u16* wph = Whi + (((size_t)(LAY) * WD + col) * WD) + khalf * 8;          \
  const u16* wpl = Wlo + (((size_t)(LAY) * WD + col) * WD) + khalf * 8;          \
  _Pragma("unroll")                                                              \
  for (int ks = 0; ks < 16; ks++){                                               \
    short8v bh = *(const short8v*)(wph + ks * 16);                               \
    short8v bl = *(const short8v*)(wpl + ks * 16);                               \
    int ce = 2 * ks + khalf;                                                     \
    _Pragma("unroll")                                                            \
    for (int mt = 0; mt < 3; mt++){                                              \
      int elem = (mt * 32 + lane31) * WD + ((ce ^ lane31) * 8);                  \
      short8v ah = *(const short8v*)(&Hhi[elem]);                                \
      short8v al = *(const short8v*)(&Hlo[elem]);                                \
      acc[mt] = __builtin_amdgcn_mfma_f32_32x32x16_bf16(ah, bh, acc[mt], 0,0,0); \
      acc[mt] = __builtin_amdgcn_mfma_f32_32x32x16_bf16(al, bh, acc[mt], 0,0,0); \
      acc[mt] = __builtin_amdgcn_mfma_f32_32x32x16_bf16(ah, bl, acc[mt], 0,0,0); \
    } } }

__launch_bounds__(NTH, 2)
__global__ void render_mfma(
    const float* pose, const float* focal, const float* nearv, const float* farv,
    const float* w0, const float* b0, const float* bsp,
    const float* vw, const float* vb,
    const float* rgbw, const float* rgbb, const float* sgw, const float* sgb,
    const float* sbeta, const float* G, const float* Bt,
    const u16* Whi, const u16* Wlo, float* out)
{
  __shared__ u16 Hhi[MP * WD];          // 48 KB
  __shared__ u16 Hlo[MP * WD];          // 48 KB
  __shared__ float xl[MP][4];
  __shared__ float vd[RPB][4];
  __shared__ float dn[RPB];
  __shared__ float sdfl[MP];
  __shared__ float rgbl[MP][4];
  __shared__ float wtl[RPB][NS];
  __shared__ float swl[WD];
  __shared__ float rwl[3][WD];

  const int t      = threadIdx.x;
  const int lane   = t & 63;
  const int wv     = t >> 6;
  const int lane31 = lane & 31;
  const int khalf  = lane >> 5;
  const int col    = wv * 32 + lane31;
  const int om     = t & 127;
  const int mg     = t >> 7;
  const int o0     = om * 2, o1 = om * 2 + 1;
  const int mb     = mg * NS;
  const int ray0   = blockIdx.x * RPB;
  const int bidx   = ray0 >> 12;

  if (t < WD) swl[t] = sgw[t];
  for (int i = t; i < 3 * WD; i += NTH) ((float*)rwl)[i] = rgbw[i];

  // ---- point setup ----
  if (t < MP){
    int m = t, s = m % NS, rl = m / NS;
    int ray = ray0 + rl;
    int ww = ray & (RESN - 1);
    int hh = (ray >> 6) & (RESN - 1);
    float f = focal[bidx], nr = nearv[bidx], fr = farv[bidx];
    float di = ((ww + 0.5f) - RESN * 0.5f) / f;
    float dj = -(((hh + 0.5f) - RESN * 0.5f) / f);
    const float* P = pose + bidx * 12;
    float rdx = di * P[0] + dj * P[1] - P[2];
    float rdy = di * P[4] + dj * P[5] - P[6];
    float rdz = di * P[8] + dj * P[9] - P[10];
    float ox = P[3], oy = P[7], oz = P[11];
    float nrm = sqrtf(rdx * rdx + rdy * rdy + rdz * rdz);
    const float C = (1.0f - 1.0f / NS) / (NS - 1);
    float tv = s * C;
    float z = nr * (1.0f - tv) + fr * tv;
    float sc = 2.0f / (fr - nr);
    xl[m][0] = (ox + rdx * z) * sc;
    xl[m][1] = (oy + rdy * z) * sc;
    xl[m][2] = (oz + rdz * z) * sc;
    if (s == 0){
      vd[rl][0] = rdx / nrm; vd[rl][1] = rdy / nrm; vd[rl][2] = rdz / nrm;
      dn[rl] = nrm;
    }
  }
  __syncthreads();

  // ---- layer 0: 3 -> 256 (VALU), writes bf16 hi/lo planes ----
  {
    float wa[3], wbv[3];
    #pragma unroll
    for (int j = 0; j < 3; j++){ wa[j] = w0[o0 * 3 + j]; wbv[j] = w0[o1 * 3 + j]; }
    float bi0 = b0[o0], bi1 = b0[o1];
    float g0 = G[bidx * WD + o0],  g1 = G[bidx * WD + o1];
    float e0 = Bt[bidx * WD + o0], e1 = Bt[bidx * WD + o1];
    #pragma unroll
    for (int m = 0; m < NS; m++){
      int row = mb + m;
      float x0 = xl[row][0], x1 = xl[row][1], x2 = xl[row][2];
      float u0 = x0 * wa[0]  + x1 * wa[1]  + x2 * wa[2]  + bi0;
      float u1 = x0 * wbv[0] + x1 * wbv[1] + x2 * wbv[2] + bi1;
      float s0 = fast_sin(fmaf(g0, u0, e0));
      float s1 = fast_sin(fmaf(g1, u1, e1));
      u32 bs0 = __float_as_uint(s0), bs1 = __float_as_uint(s1);
      u32 hw = (bs0 >> 16) | (bs1 & 0xFFFF0000u);
      float l0f = s0 - __uint_as_float(bs0 & 0xFFFF0000u);
      float l1f = s1 - __uint_as_float(bs1 & 0xFFFF0000u);
      u32 lw = (__float_as_uint(l0f) >> 16) | (__float_as_uint(l1f) & 0xFFFF0000u);
      int eidx = row * WD + (((o0 >> 3) ^ (row & 31)) * 8) + (o0 & 7);
      *(u32*)&Hhi[eidx] = hw;
      *(u32*)&Hlo[eidx] = lw;
    }
  }
  __syncthreads();

  // ---- 7 hidden layers via MFMA ----
  #pragma unroll 1
  for (int l = 0; l < 7; l++){
    f32x16 acc[3];
    #pragma unroll
    for (int mt = 0; mt < 3; mt++)
      #pragma unroll
      for (int j = 0; j < 16; j++) acc[mt][j] = 0.f;
    KMAIN(l)
    float g  = G[((l + 1) * NB + bidx) * WD + col];
    float e  = Bt[((l + 1) * NB + bidx) * WD + col];
    float bi = bsp[l * WD + col];
    __syncthreads();   // everyone done reading planes
    #pragma unroll
    for (int mt = 0; mt < 3; mt++){
      #pragma unroll
      for (int rg = 0; rg < 16; rg++){
        int row = mt * 32 + (rg & 3) + 8 * (rg >> 2) + 4 * khalf;
        float a = acc[mt][rg] + bi;
        float s = fast_sin(fmaf(g, a, e));
        u32 sb = __float_as_uint(s);
        int eidx = row * WD + ((((col >> 3) ^ (row & 31))) * 8) + (col & 7);
        Hhi[eidx] = (u16)(sb >> 16);
        float sl = s - __uint_as_float(sb & 0xFFFF0000u);
        Hlo[eidx] = (u16)(__float_as_uint(sl) >> 16);
      }
    }
    __syncthreads();
  }

  // ---- view layer K-loop (lay 7 of planes) ----
  f32x16 acc[3];
  #pragma unroll
  for (int mt = 0; mt < 3; mt++)
    #pragma unroll
    for (int j = 0; j < 16; j++) acc[mt][j] = 0.f;
  KMAIN(7)
  // view tail weights (cols 256..258) + bias, per output col
  float vt0 = vw[(size_t)col * 259 + 256];
  float vt1 = vw[(size_t)col * 259 + 257];
  float vt2 = vw[(size_t)col * 259 + 258];
  float vbv = vb[col];
  float gv = G[(8 * NB + bidx) * WD + col];
  float ev = Bt[(8 * NB + bidx) * WD + col];

  // ---- sigma head (reads layer-7 planes, before epilogue overwrites) ----
  if (t < MP){
    float a = 0.f;
    #pragma unroll 4
    for (int c = 0; c < 32; c++){
      int eb = t * WD + ((c ^ (t & 31)) * 8);
      short8v hv = *(const short8v*)(&Hhi[eb]);
      short8v lv = *(const short8v*)(&Hlo[eb]);
      #pragma unroll
      for (int j = 0; j < 8; j++){
        float h = __uint_as_float(((u32)(u16)hv[j]) << 16)
                + __uint_as_float(((u32)(u16)lv[j]) << 16);
        a = fmaf(h, swl[c * 8 + j], a);
      }
    }
    sdfl[t] = a + sgb[0];
  }
  __syncthreads();

  // ---- view epilogue: feat = sin(g*(acc + dir-term) + e) -> planes ----
  #pragma unroll
  for (int mt = 0; mt < 3; mt++){
    #pragma unroll
    for (int rg = 0; rg < 16; rg++){
      int row = mt * 32 + (rg & 3) + 8 * (rg >> 2) + 4 * khalf;
      int ray = (row >= 48) ? ((row >= 72) ? 3 : 2) : ((row >= 24) ? 1 : 0);
      float c = vd[ray][0] * vt0 + vd[ray][1] * vt1 + vd[ray][2] * vt2 + vbv;
      float a = acc[mt][rg] + c;
      float s = fast_sin(fmaf(gv, a, ev));
      u32 sb = __float_as_uint(s);
      int eidx = row * WD + ((((col >> 3) ^ (row & 31))) * 8) + (col & 7);
      Hhi[eidx] = (u16)(sb >> 16);
      float sl = s - __uint_as_float(sb & 0xFFFF0000u);
      Hlo[eidx] = (u16)(__float_as_uint(sl) >> 16);
    }
  }
  __syncthreads();

  // ---- rgb head (reads feat planes) ----
  if (t < MP){
    float a0 = 0.f, a1 = 0.f, a2 = 0.f;
    #pragma unroll 4
    for (int c = 0; c < 32; c++){
      int eb = t * WD + ((c ^ (t & 31)) * 8);
      short8v hv = *(const short8v*)(&Hhi[eb]);
      short8v lv = *(const short8v*)(&Hlo[eb]);
      #pragma unroll
      for (int j = 0; j < 8; j++){
        float h = __uint_as_float(((u32)(u16)hv[j]) << 16)
                + __uint_as_float(((u32)(u16)lv[j]) << 16);
        int k = c * 8 + j;
        a0 = fmaf(h, rwl[0][k], a0);
        a1 = fmaf(h, rwl[1][k], a1);
        a2 = fmaf(h, rwl[2][k], a2);
      }
    }
    rgbl[t][0] = a0 + rgbb[0];
    rgbl[t][1] = a1 + rgbb[1];
    rgbl[t][2] = a2 + rgbb[2];
  }
  __syncthreads();

  // ---- volume integration weights + rgb_map (one thread per ray) ----
  if (t < RPB){
    int r = t;
    int ray = ray0 + r;
    float nr = nearv[bidx], fr = farv[bidx];
    float dnv = dn[r];
    float bet = sbeta[0];
    float vis = 1.f, wsum = 0.f, cr = 0.f, cg = 0.f, cb = 0.f;
    const float C = (1.0f - 1.0f / NS) / (NS - 1);
    #pragma unroll
    for (int s = 0; s < NS; s++){
      float w;
      if (s < NS - 1){
        float t0v = s * C, t1v = (s + 1) * C;
        float z0 = nr * (1.f - t0v) + fr * t0v;
        float z1 = nr * (1.f - t1v) + fr * t1v;
        float dist = (z1 - z0) * dnv;
        float sg = sigm(-sdfl[r * NS + s] / bet) / bet;
        float al = 1.f - expf(-sg * dist);
        w = al * vis;
        vis *= (1.f - al + 1e-10f);
        wsum += w;
      } else {
        w = 1.f - wsum;
      }
      wtl[r][s] = w;
      cr += w * sigm(rgbl[r * NS + s][0]);
      cg += w * sigm(rgbl[r * NS + s][1]);
      cb += w * sigm(rgbl[r * NS + s][2]);
    }
    size_t ob = (size_t)ray * 259;
    out[ob + 0] = -1.f + 2.f * cr;
    out[ob + 1] = -1.f + 2.f * cg;
    out[ob + 2] = -1.f + 2.f * cb;
  }
  __syncthreads();

  // ---- feature map: sum_s w_s * feat_s ----
  {
    float f0 = 0.f, f1 = 0.f;
    #pragma unroll
    for (int s = 0; s < NS; s++){
      int row = mb + s;
      float w = wtl[mg][s];
      int eidx = row * WD + (((o0 >> 3) ^ (row & 31)) * 8) + (o0 & 7);
      u32 wh = *(const u32*)&Hhi[eidx];
      u32 wl = *(const u32*)&Hlo[eidx];
      float fa = __uint_as_float(wh << 16) + __uint_as_float(wl << 16);
      float fb = __uint_as_float(wh & 0xFFFF0000u) + __uint_as_float(wl & 0xFFFF0000u);
      f0 = fmaf(w, fa, f0);
      f1 = fmaf(w, fb, f1);
    }
    size_t ob = (size_t)(ray0 + mg) * 259 + 3;
    out[ob + o0] = f0;
    out[ob + o1] = f1;
  }
}

extern "C" void kernel_launch(void* const* d_in, const int* in_sizes, int n_in,
                              void* d_out, int out_size, void* d_ws, size_t ws_size,
                              hipStream_t stream) {
  (void)in_sizes; (void)n_in; (void)out_size; (void)ws_size;
  const float* pose   = (const float*)d_in[0];
  const float* focal  = (const float*)d_in[1];
  const float* nearv  = (const float*)d_in[2];
  const float* farv   = (const float*)d_in[3];
  const float* styles = (const float*)d_in[4];
  const float* w0     = (const float*)d_in[5];
  const float* b0     = (const float*)d_in[6];
  const float* wsp    = (const float*)d_in[7];
  const float* bsp    = (const float*)d_in[8];
  const float* gw8    = (const float*)d_in[9];
  const float* gb8    = (const float*)d_in[10];
  const float* bw8    = (const float*)d_in[11];
  const float* bb8    = (const float*)d_in[12];
  const float* vw     = (const float*)d_in[13];
  const float* vb     = (const float*)d_in[14];
  const float* vgw    = (const float*)d_in[15];
  const float* vgb    = (const float*)d_in[16];
  const float* vbw    = (const float*)d_in[17];
  const float* vbb    = (const float*)d_in[18];
  const float* rgbw   = (const float*)d_in[19];
  const float* rgbb   = (const float*)d_in[20];
  const float* sgw    = (const float*)d_in[21];
  const float* sgb    = (const float*)d_in[22];
  const float* sbeta  = (const float*)d_in[23];

  float* G  = (float*)d_ws;
  float* Bt = G + 9 * NB * WD;                       // 4608 floats
  float* out = (float*)d_out;

  const size_t plane_off = 36864;                    // bytes (G+Bt)
  const size_t plane_elems = (size_t)8 * WD * WD;    // 524288 u16 per plane

  u16* Whi = (u16*)((char*)d_ws + plane_off);
  u16* Wlo = Whi + plane_elems;

  film_kernel<<<dim3(18), dim3(256), 0, stream>>>(styles, gw8, gb8, bw8, bb8,
                                                  vgw, vgb, vbw, vbb, G, Bt);
  prep_kernel<<<dim3(512), dim3(256), 0, stream>>>(wsp, vw, Whi, Wlo);
  render_mfma<<<dim3(NBLK), dim3(NTH), 0, stream>>>(pose, focal, nearv, farv,
      w0, b0, bsp, vw, vb, rgbw, rgbb, sgw, sgb, sbeta, G, Bt, Whi, Wlo, out);
}

// Round 15
// 839.557 us; speedup vs baseline: 1.1060x; 1.0759x over previous
//
#include <hip/hip_runtime.h>
#include <hip/hip_bf16.h>

#define RESN 64
#define NS 24
#define WD 256
#define SD 256
#define NB 2
#define RPB 4          // rays per block
#define MP 96          // points per block = RPB*NS
#define NTH 512
#define NBLK 2048      // (NB*RESN*RESN)/RPB

typedef unsigned short u16;
typedef unsigned int u32;
typedef __attribute__((ext_vector_type(8))) short short8v;   // 8 bf16 (4 VGPRs)
typedef __attribute__((ext_vector_type(16))) float f32x16;   // MFMA 32x32 accumulator

__device__ __forceinline__ float sigm(float x){ return 1.0f / (1.0f + expf(-x)); }

// range-reduced odd deg-9 sin, |x| <= ~100, abs err ~4e-6
__device__ __forceinline__ float fast_sin(float x){
  float k = __builtin_rintf(x * 0.31830988618f);
  float y = fmaf(k, -3.14159274101f, x);
  y = fmaf(k, 8.74227766e-8f, y);
  float y2 = y * y;
  float p = fmaf(y2, 2.75573192e-6f, -1.98412698e-4f);
  p = fmaf(y2, p, 8.33333333e-3f);
  p = fmaf(y2, p, -1.66666667e-1f);
  float s = fmaf(y * y2, p, y);
  u32 sg = ((u32)((int)k) & 1u) << 31;
  return __uint_as_float(__float_as_uint(s) ^ sg);
}

// ---------------- kernel 0: split fp32 weights into bf16 hi/lo planes ----------------
__global__ void prep_kernel(const float* wsp, const float* vw, u16* Whi, u16* Wlo){
  int i0 = (blockIdx.x * 256 + threadIdx.x) * 4;
  #pragma unroll
  for (int j = 0; j < 4; j++){
    int e = i0 + j;
    int lay = e >> 16;
    int rk = e & 65535;
    float w = (lay < 7) ? wsp[lay * 65536 + rk]
                        : vw[(size_t)(rk >> 8) * 259 + (rk & 255)];
    u32 b = __float_as_uint(w);
    u16 hi = (u16)(b >> 16);
    float lof = w - __uint_as_float(b & 0xFFFF0000u);
    Whi[e] = hi;
    Wlo[e] = (u16)(__float_as_uint(lof) >> 16);
  }
}

// ---------------- kernel 1: FiLM gamma/beta per (layer, batch, out) ----------------
__global__ void film_kernel(const float* styles, const float* gw8, const float* gb8,
                            const float* bw8, const float* bb8,
                            const float* vgw, const float* vgb, const float* vbw, const float* vbb,
                            float* G, float* Bt){
  int l = blockIdx.x >> 1, b = blockIdx.x & 1, o = threadIdx.x;
  __shared__ float st[SD];
  st[o] = styles[b * SD + o];
  __syncthreads();
  const float *gw, *bw; float gbv, bbv;
  if (l < 8){
    gw = gw8 + ((size_t)l * WD + o) * SD; bw = bw8 + ((size_t)l * WD + o) * SD;
    gbv = gb8[l * WD + o];                bbv = bb8[l * WD + o];
  } else {
    gw = vgw + (size_t)o * SD;            bw = vbw + (size_t)o * SD;
    gbv = vgb[o];                         bbv = vbb[o];
  }
  float ag = 0.f, ab = 0.f;
  for (int s = 0; s < SD; s += 2){
    ag += st[s] * gw[s] + st[s+1] * gw[s+1];
    ab += st[s] * bw[s] + st[s+1] * bw[s+1];
  }
  int idx = (l * NB + b) * WD + o;
  G[idx]  = 15.0f * (ag + gbv) + 30.0f;
  Bt[idx] = 0.25f * (ab + bbv);
}

// ---------------- kernel 2: fused MFMA renderer ----------------
// 512 threads = 8 waves. Wave w owns output cols [w*32, w*32+32).
// KMAIN interleave: product-type outer, tile inner -> distance-3 between
// dependent MFMAs on the same accumulator; per-acc op order unchanged
// (hh, lh, hl per ks) -> bit-identical numerics vs round 5.
#define SETW(LAY) { wph = Whi + (((size_t)(LAY) * WD + col) * WD) + khalf * 8;   \
                    wpl = Wlo + (((size_t)(LAY) * WD + col) * WD) + khalf * 8; }

#define PREF4 { _Pragma("unroll")                                                \
  for (int i = 0; i < 4; i++){                                                   \
    pbh[i] = *(const short8v*)(wph + i * 16);                                    \
    pbl[i] = *(const short8v*)(wpl + i * 16); } }

#define KMAIN                                                                    \
  _Pragma("unroll")                                                              \
  for (int ks = 0; ks < 16; ks++){                                               \
    short8v bh = pbh[ks & 3], bl = pbl[ks & 3];                                  \
    if (ks < 12){ pbh[ks & 3] = *(const short8v*)(wph + (ks + 4) * 16);          \
                  pbl[ks & 3] = *(const short8v*)(wpl + (ks + 4) * 16); }        \
    int ce = 2 * ks + khalf;                                                     \
    int e0 = (lane31) * WD + ((ce ^ l7) * 8);                                    \
    int e1 = (32 + lane31) * WD + ((ce ^ l7) * 8);                               \
    int e2 = (64 + lane31) * WD + ((ce ^ l7) * 8);                               \
    short8v ah0 = *(const short8v*)(&Hhi[e0]);                                   \
    short8v ah1 = *(const short8v*)(&Hhi[e1]);                                   \
    short8v ah2 = *(const short8v*)(&Hhi[e2]);                                   \
    short8v al0 = *(const short8v*)(&Hlo[e0]);                                   \
    short8v al1 = *(const short8v*)(&Hlo[e1]);                                   \
    short8v al2 = *(const short8v*)(&Hlo[e2]);                                   \
    acc0 = __builtin_amdgcn_mfma_f32_32x32x16_bf16(ah0, bh, acc0, 0,0,0);        \
    acc1 = __builtin_amdgcn_mfma_f32_32x32x16_bf16(ah1, bh, acc1, 0,0,0);        \
    acc2 = __builtin_amdgcn_mfma_f32_32x32x16_bf16(ah2, bh, acc2, 0,0,0);        \
    acc0 = __builtin_amdgcn_mfma_f32_32x32x16_bf16(al0, bh, acc0, 0,0,0);        \
    acc1 = __builtin_amdgcn_mfma_f32_32x32x16_bf16(al1, bh, acc1, 0,0,0);        \
    acc2 = __builtin_amdgcn_mfma_f32_32x32x16_bf16(al2, bh, acc2, 0,0,0);        \
    acc0 = __builtin_amdgcn_mfma_f32_32x32x16_bf16(ah0, bl, acc0, 0,0,0);        \
    acc1 = __builtin_amdgcn_mfma_f32_32x32x16_bf16(ah1, bl, acc1, 0,0,0);        \
    acc2 = __builtin_amdgcn_mfma_f32_32x32x16_bf16(ah2, bl, acc2, 0,0,0);        \
  }

#define ZACC3 { _Pragma("unroll") for (int j_ = 0; j_ < 16; j_++){               \
    acc0[j_] = 0.f; acc1[j_] = 0.f; acc2[j_] = 0.f; } }

__launch_bounds__(NTH, 2)
__global__ void render_mfma(
    const float* pose, const float* focal, const float* nearv, const float* farv,
    const float* w0, const float* b0, const float* bsp,
    const float* vw, const float* vb,
    const float* rgbw, const float* rgbb, const float* sgw, const float* sgb,
    const float* sbeta, const float* G, const float* Bt,
    const u16* Whi, const u16* Wlo, float* out)
{
  __shared__ u16 Hhi[MP * WD];          // 48 KB
  __shared__ u16 Hlo[MP * WD];          // 48 KB
  __shared__ float xl[MP][4];
  __shared__ float vd[RPB][4];
  __shared__ float dn[RPB];
  __shared__ float sdfl[MP];
  __shared__ float rgbl[MP][4];
  __shared__ float wtl[RPB][NS];
  __shared__ float swl[WD];
  __shared__ float rwl[3][WD];

  const int t      = threadIdx.x;
  const int lane   = t & 63;
  const int wv     = t >> 6;
  const int lane31 = lane & 31;
  const int khalf  = lane >> 5;
  const int l7     = lane31 & 7;
  const int col    = wv * 32 + lane31;
  const int om     = t & 127;
  const int mg     = t >> 7;
  const int o0     = om * 2, o1 = om * 2 + 1;
  const int mb     = mg * NS;
  const int ray0   = blockIdx.x * RPB;
  const int bidx   = ray0 >> 12;

  // B prefetch state (persists across layers)
  const u16 *wph, *wpl;
  short8v pbh[4], pbl[4];
  SETW(0); PREF4;                      // layer-0 weights fly during setup

  f32x16 acc0, acc1, acc2;

  if (t < WD) swl[t] = sgw[t];
  for (int i = t; i < 3 * WD; i += NTH) ((float*)rwl)[i] = rgbw[i];

  // ---- point setup ----
  if (t < MP){
    int m = t, s = m % NS, rl = m / NS;
    int ray = ray0 + rl;
    int ww = ray & (RESN - 1);
    int hh = (ray >> 6) & (RESN - 1);
    float f = focal[bidx], nr = nearv[bidx], fr = farv[bidx];
    float di = ((ww + 0.5f) - RESN * 0.5f) / f;
    float dj = -(((hh + 0.5f) - RESN * 0.5f) / f);
    const float* P = pose + bidx * 12;
    float rdx = di * P[0] + dj * P[1] - P[2];
    float rdy = di * P[4] + dj * P[5] - P[6];
    float rdz = di * P[8] + dj * P[9] - P[10];
    float ox = P[3], oy = P[7], oz = P[11];
    float nrm = sqrtf(rdx * rdx + rdy * rdy + rdz * rdz);
    const float C = (1.0f - 1.0f / NS) / (NS - 1);
    float tv = s * C;
    float z = nr * (1.0f - tv) + fr * tv;
    float sc = 2.0f / (fr - nr);
    xl[m][0] = (ox + rdx * z) * sc;
    xl[m][1] = (oy + rdy * z) * sc;
    xl[m][2] = (oz + rdz * z) * sc;
    if (s == 0){
      vd[rl][0] = rdx / nrm; vd[rl][1] = rdy / nrm; vd[rl][2] = rdz / nrm;
      dn[rl] = nrm;
    }
  }
  __syncthreads();

  // ---- layer 0: 3 -> 256 (VALU), writes bf16 hi/lo planes ----
  {
    float wa[3], wbv[3];
    #pragma unroll
    for (int j = 0; j < 3; j++){ wa[j] = w0[o0 * 3 + j]; wbv[j] = w0[o1 * 3 + j]; }
    float bi0 = b0[o0], bi1 = b0[o1];
    float g0 = G[bidx * WD + o0],  g1 = G[bidx * WD + o1];
    float e0 = Bt[bidx * WD + o0], e1 = Bt[bidx * WD + o1];
    #pragma unroll
    for (int m = 0; m < NS; m++){
      int row = mb + m;
      float x0 = xl[row][0], x1 = xl[row][1], x2 = xl[row][2];
      float u0 = x0 * wa[0]  + x1 * wa[1]  + x2 * wa[2]  + bi0;
      float u1 = x0 * wbv[0] + x1 * wbv[1] + x2 * wbv[2] + bi1;
      float s0 = fast_sin(fmaf(g0, u0, e0));
      float s1 = fast_sin(fmaf(g1, u1, e1));
      u32 bs0 = __float_as_uint(s0), bs1 = __float_as_uint(s1);
      u32 hw = (bs0 >> 16) | (bs1 & 0xFFFF0000u);
      float l0f = s0 - __uint_as_float(bs0 & 0xFFFF0000u);
      float l1f = s1 - __uint_as_float(bs1 & 0xFFFF0000u);
      u32 lw = (__float_as_uint(l0f) >> 16) | (__float_as_uint(l1f) & 0xFFFF0000u);
      int eidx = row * WD + (((o0 >> 3) ^ (row & 7)) * 8) + (o0 & 7);
      *(u32*)&Hhi[eidx] = hw;
      *(u32*)&Hlo[eidx] = lw;
    }
  }
  __syncthreads();

  // ---- 7 hidden layers via MFMA ----
  #pragma unroll 1
  for (int l = 0; l < 7; l++){
    ZACC3
    KMAIN
    float g  = G[((l + 1) * NB + bidx) * WD + col];
    float e  = Bt[((l + 1) * NB + bidx) * WD + col];
    float bi = bsp[l * WD + col];
    __syncthreads();   // everyone done reading planes
    #pragma unroll
    for (int mt = 0; mt < 3; mt++){
      #pragma unroll
      for (int rg = 0; rg < 16; rg++){
        int row = mt * 32 + (rg & 3) + 8 * (rg >> 2) + 4 * khalf;
        float av = (mt == 0) ? acc0[rg] : (mt == 1) ? acc1[rg] : acc2[rg];
        float a = av + bi;
        float s = fast_sin(fmaf(g, a, e));
        u32 sb = __float_as_uint(s);
        int eidx = row * WD + ((((col >> 3) ^ (row & 7))) * 8) + (col & 7);
        Hhi[eidx] = (u16)(sb >> 16);
        float sl = s - __uint_as_float(sb & 0xFFFF0000u);
        Hlo[eidx] = (u16)(__float_as_uint(sl) >> 16);
      }
    }
    SETW(l + 1); PREF4;   // next layer's (or view layer's) first 4 B-chunks
    __syncthreads();
  }

  // ---- view layer K-loop (lay 7 of planes, prefetched in last iteration) ----
  ZACC3
  KMAIN
  // view tail weights (cols 256..258) + bias, per output col
  float vt0 = vw[(size_t)col * 259 + 256];
  float vt1 = vw[(size_t)col * 259 + 257];
  float vt2 = vw[(size_t)col * 259 + 258];
  float vbv = vb[col];
  float gv = G[(8 * NB + bidx) * WD + col];
  float ev = Bt[(8 * NB + bidx) * WD + col];

  // ---- sigma head (reads layer-7 planes, before epilogue overwrites) ----
  if (t < MP){
    float a = 0.f;
    #pragma unroll 4
    for (int c = 0; c < 32; c++){
      int eb = t * WD + ((c ^ (t & 7)) * 8);
      short8v hv = *(const short8v*)(&Hhi[eb]);
      short8v lv = *(const short8v*)(&Hlo[eb]);
      #pragma unroll
      for (int j = 0; j < 8; j++){
        float h = __uint_as_float(((u32)(u16)hv[j]) << 16)
                + __uint_as_float(((u32)(u16)lv[j]) << 16);
        a = fmaf(h, swl[c * 8 + j], a);
      }
    }
    sdfl[t] = a + sgb[0];
  }
  __syncthreads();

  // ---- view epilogue: feat = sin(g*(acc + dir-term) + e) -> planes ----
  #pragma unroll
  for (int mt = 0; mt < 3; mt++){
    #pragma unroll
    for (int rg = 0; rg < 16; rg++){
      int row = mt * 32 + (rg & 3) + 8 * (rg >> 2) + 4 * khalf;
      int ray = (row >= 48) ? ((row >= 72) ? 3 : 2) : ((row >= 24) ? 1 : 0);
      float c = vd[ray][0] * vt0 + vd[ray][1] * vt1 + vd[ray][2] * vt2 + vbv;
      float av = (mt == 0) ? acc0[rg] : (mt == 1) ? acc1[rg] : acc2[rg];
      float a = av + c;
      float s = fast_sin(fmaf(gv, a, ev));
      u32 sb = __float_as_uint(s);
      int eidx = row * WD + ((((col >> 3) ^ (row & 7))) * 8) + (col & 7);
      Hhi[eidx] = (u16)(sb >> 16);
      float sl = s - __uint_as_float(sb & 0xFFFF0000u);
      Hlo[eidx] = (u16)(__float_as_uint(sl) >> 16);
    }
  }
  __syncthreads();

  // ---- rgb head (reads feat planes) ----
  if (t < MP){
    float a0 = 0.f, a1 = 0.f, a2 = 0.f;
    #pragma unroll 4
    for (int c = 0; c < 32; c++){
      int eb = t * WD + ((c ^ (t & 7)) * 8);
      short8v hv = *(const short8v*)(&Hhi[eb]);
      short8v lv = *(const short8v*)(&Hlo[eb]);
      #pragma unroll
      for (int j = 0; j < 8; j++){
        float h = __uint_as_float(((u32)(u16)hv[j]) << 16)
                + __uint_as_float(((u32)(u16)lv[j]) << 16);
        int k = c * 8 + j;
        a0 = fmaf(h, rwl[0][k], a0);
        a1 = fmaf(h, rwl[1][k], a1);
        a2 = fmaf(h, rwl[2][k], a2);
      }
    }
    rgbl[t][0] = a0 + rgbb[0];
    rgbl[t][1] = a1 + rgbb[1];
    rgbl[t][2] = a2 + rgbb[2];
  }
  __syncthreads();

  // ---- volume integration weights + rgb_map (one thread per ray) ----
  if (t < RPB){
    int r = t;
    int ray = ray0 + r;
    float nr = nearv[bidx], fr = farv[bidx];
    float dnv = dn[r];
    float bet = sbeta[0];
    float vis = 1.f, wsum = 0.f, cr = 0.f, cg = 0.f, cb = 0.f;
    const float C = (1.0f - 1.0f / NS) / (NS - 1);
    #pragma unroll
    for (int s = 0; s < NS; s++){
      float w;
      if (s < NS - 1){
        float t0v = s * C, t1v = (s + 1) * C;
        float z0 = nr * (1.f - t0v) + fr * t0v;
        float z1 = nr * (1.f - t1v) + fr * t1v;
        float dist = (z1 - z0) * dnv;
        float sg = sigm(-sdfl[r * NS + s] / bet) / bet;
        float al = 1.f - expf(-sg * dist);
        w = al * vis;
        vis *= (1.f - al + 1e-10f);
        wsum += w;
      } else {
        w = 1.f - wsum;
      }
      wtl[r][s] = w;
      cr += w * sigm(rgbl[r * NS + s][0]);
      cg += w * sigm(rgbl[r * NS + s][1]);
      cb += w * sigm(rgbl[r * NS + s][2]);
    }
    size_t ob = (size_t)ray * 259;
    out[ob + 0] = -1.f + 2.f * cr;
    out[ob + 1] = -1.f + 2.f * cg;
    out[ob + 2] = -1.f + 2.f * cb;
  }
  __syncthreads();

  // ---- feature map: sum_s w_s * feat_s ----
  {
    float f0 = 0.f, f1 = 0.f;
    #pragma unroll
    for (int s = 0; s < NS; s++){
      int row = mb + s;
      float w = wtl[mg][s];
      int eidx = row * WD + (((o0 >> 3) ^ (row & 7)) * 8) + (o0 & 7);
      u32 wh = *(const u32*)&Hhi[eidx];
      u32 wl = *(const u32*)&Hlo[eidx];
      float fa = __uint_as_float(wh << 16) + __uint_as_float(wl << 16);
      float fb = __uint_as_float(wh & 0xFFFF0000u) + __uint_as_float(wl & 0xFFFF0000u);
      f0 = fmaf(w, fa, f0);
      f1 = fmaf(w, fb, f1);
    }
    size_t ob = (size_t)(ray0 + mg) * 259 + 3;
    out[ob + o0] = f0;
    out[ob + o1] = f1;
  }
}

extern "C" void kernel_launch(void* const* d_in, const int* in_sizes, int n_in,
                              void* d_out, int out_size, void* d_ws, size_t ws_size,
                              hipStream_t stream) {
  (void)in_sizes; (void)n_in; (void)out_size; (void)ws_size;
  const float* pose   = (const float*)d_in[0];
  const float* focal  = (const float*)d_in[1];
  const float* nearv  = (const float*)d_in[2];
  const float* farv   = (const float*)d_in[3];
  const float* styles = (const float*)d_in[4];
  const float* w0     = (const float*)d_in[5];
  const float* b0     = (const float*)d_in[6];
  const float* wsp    = (const float*)d_in[7];
  const float* bsp    = (const float*)d_in[8];
  const float* gw8    = (const float*)d_in[9];
  const float* gb8    = (const float*)d_in[10];
  const float* bw8    = (const float*)d_in[11];
  const float* bb8    = (const float*)d_in[12];
  const float* vw     = (const float*)d_in[13];
  const float* vb     = (const float*)d_in[14];
  const float* vgw    = (const float*)d_in[15];
  const float* vgb    = (const float*)d_in[16];
  const float* vbw    = (const float*)d_in[17];
  const float* vbb    = (const float*)d_in[18];
  const float* rgbw   = (const float*)d_in[19];
  const float* rgbb   = (const float*)d_in[20];
  const float* sgw    = (const float*)d_in[21];
  const float* sgb    = (const float*)d_in[22];
  const float* sbeta  = (const float*)d_in[23];

  float* G  = (float*)d_ws;
  float* Bt = G + 9 * NB * WD;                       // 4608 floats
  float* out = (float*)d_out;

  const size_t plane_off = 36864;                    // bytes (G+Bt)
  const size_t plane_elems = (size_t)8 * WD * WD;    // 524288 u16 per plane

  u16* Whi = (u16*)((char*)d_ws + plane_off);
  u16* Wlo = Whi + plane_elems;

  film_kernel<<<dim3(18), dim3(256), 0, stream>>>(styles, gw8, gb8, bw8, bb8,
                                                  vgw, vgb, vbw, vbb, G, Bt);
  prep_kernel<<<dim3(512), dim3(256), 0, stream>>>(wsp, vw, Whi, Wlo);
  render_mfma<<<dim3(NBLK), dim3(NTH), 0, stream>>>(pose, focal, nearv, farv,
      w0, b0, bsp, vw, vb, rgbw, rgbb, sgw, sgb, sbeta, G, Bt, Whi, Wlo, out);
}